// Round 8
// baseline (641.357 us; speedup 1.0000x reference)
//
#include <hip/hip_runtime.h>
#include <cstdint>
#include <cstddef>

#define S_TOK 8192
#define MDIM  2048
#define NE    64
#define CAP   128
#define NSEG  512    // 16-token segments, one per gemm-role block
#define KC    32
#define RT    16

typedef float f32x4 __attribute__((ext_vector_type(4)));

// d_out float layout: [0]=l_aux | [1..+67108864)=combine | [..+67108864)=dispatch | [..+64)=exp_counts
static const size_t COMBINE_OFF  = 1;
static const size_t DISPATCH_OFF = 1 + 67108864ULL;
static const size_t COUNTS_OFF   = 1 + 2ULL * 67108864ULL;   // = 134217729

// ---------------------------------------------------------------- kernel 1: role-split
// 640 blocks. bid%5==4 (128 blocks): pure zero-fill of d_out, barrier-free nontemporal
// stores -> store pipe never stalls on a vmcnt(0)+s_barrier drain. Other 512 blocks:
// full-K GEMM for 16 rows (thread = 1 row x 4 experts), fused softmax/argmax/colsum-
// partial/segment-histogram epilogue (rows are block-local with full K).
__global__ __launch_bounds__(256) void k_main(const float* __restrict__ in,
                                              const float* __restrict__ wg,
                                              f32x4* __restrict__ zout,
                                              float* __restrict__ gate_sel,
                                              int* __restrict__ eid,
                                              int* __restrict__ segcnt,
                                              float* __restrict__ colpart) {
    int t = threadIdx.x;
    int bid = blockIdx.x;
    const f32x4 z4 = {0.f, 0.f, 0.f, 0.f};
    if ((bid % 5) == 4) {                          // ---- fill role
        long i = (long)(bid / 5) * 256 + t;        // [0, 32768)
        #pragma unroll 4
        for (; i < 33554448L; i += 32768L)         // covers floats [0, 134217792)
            __builtin_nontemporal_store(z4, zout + i);
        return;
    }
    // ---- gemm role
    int g = (bid / 5) * 4 + (bid % 5);             // [0, 512)
    __shared__ float in_lds[KC][RT + 4];
    __shared__ float wg_lds[KC][NE + 4];
    __shared__ float ls[NE];
    __shared__ int hist[NE];
    if (t < NE) { ls[t] = 0.f; hist[t] = 0; }
    int r0 = g * RT;
    int te = t & 15, tr = t >> 4;                  // expert group te*4.., row r0+tr
    int kq = t & 7;                                // float4 group along k
    int erow = t >> 3;                             // 0..31
    float acc[4] = {0.f, 0.f, 0.f, 0.f};
    for (int c = 0; c < 64; ++c) {
        int k0 = c * KC;
        float4 w0 = *(const float4*)(wg + (size_t)erow * MDIM + k0 + kq * 4);
        float4 w1 = *(const float4*)(wg + (size_t)(erow + 32) * MDIM + k0 + kq * 4);
        float4 v;
        if (t < 128)
            v = *(const float4*)(in + (size_t)(r0 + erow) * MDIM + k0 + kq * 4);
        wg_lds[kq * 4 + 0][erow] = w0.x; wg_lds[kq * 4 + 1][erow] = w0.y;
        wg_lds[kq * 4 + 2][erow] = w0.z; wg_lds[kq * 4 + 3][erow] = w0.w;
        wg_lds[kq * 4 + 0][erow + 32] = w1.x; wg_lds[kq * 4 + 1][erow + 32] = w1.y;
        wg_lds[kq * 4 + 2][erow + 32] = w1.z; wg_lds[kq * 4 + 3][erow + 32] = w1.w;
        if (t < 128) {
            in_lds[kq * 4 + 0][erow] = v.x; in_lds[kq * 4 + 1][erow] = v.y;
            in_lds[kq * 4 + 2][erow] = v.z; in_lds[kq * 4 + 3][erow] = v.w;
        }
        __syncthreads();
        #pragma unroll
        for (int kk = 0; kk < KC; ++kk) {
            float a = in_lds[kk][tr];
            float4 b4 = *(const float4*)&wg_lds[kk][te * 4];
            acc[0] += a * b4.x; acc[1] += a * b4.y;
            acc[2] += a * b4.z; acc[3] += a * b4.w;
        }
        __syncthreads();
    }
    // ---- epilogue: softmax + first-index argmax across the 16-lane expert group
    int r = r0 + tr;
    float m = acc[0]; int mj = 0;
    #pragma unroll
    for (int j = 1; j < 4; ++j) if (acc[j] > m) { m = acc[j]; mj = j; }
    int mi = te * 4 + mj;
    #pragma unroll
    for (int off = 1; off < 16; off <<= 1) {
        float om = __shfl_xor(m, off);
        int   oi = __shfl_xor(mi, off);
        if (om > m || (om == m && oi < mi)) { m = om; mi = oi; }
    }
    float ex[4]; float lsum = 0.f;
    #pragma unroll
    for (int j = 0; j < 4; ++j) { ex[j] = expf(acc[j] - m); lsum += ex[j]; }
    float s = lsum;
    #pragma unroll
    for (int off = 1; off < 16; off <<= 1) s += __shfl_xor(s, off);
    if ((mi >> 2) == te) {                         // winner thread for this row
        gate_sel[r] = ex[mi & 3] / s;
        eid[r] = mi;
        atomicAdd(&hist[mi], 1);
    }
    #pragma unroll
    for (int j = 0; j < 4; ++j) atomicAdd(&ls[te * 4 + j], ex[j] / s);
    __syncthreads();
    if (t < NE) {
        segcnt[t * NSEG + g] = hist[t];            // [e][seg]
        colpart[(size_t)g * NE + t] = ls[t];       // [seg][e]
    }
}

// ---------------------------------------------------------------- kernel 2: scan + scatter + counts + l_aux
// Block e: pair-wise load of 512 segment counts -> block exclusive scan (1 barrier),
// thread t walks its 32-token range with a running rank; colsum reduced from colpart.
__global__ __launch_bounds__(256) void k_scan_scatter(const int* __restrict__ segcnt,
                                                      const float* __restrict__ gate_sel,
                                                      const int* __restrict__ eid,
                                                      const float* __restrict__ colpart,
                                                      float* __restrict__ out) {
    __shared__ int wsum[4];
    __shared__ float wsumf[4];
    int e = blockIdx.x;
    int t = threadIdx.x;
    int lane = t & 63, w = t >> 6;
    int c0 = segcnt[e * NSEG + 2 * t];
    int c1 = segcnt[e * NSEG + 2 * t + 1];
    int c = c0 + c1;
    float f = colpart[(size_t)(2 * t) * NE + e] + colpart[(size_t)(2 * t + 1) * NE + e];
    int incl = c;
    #pragma unroll
    for (int off = 1; off < 64; off <<= 1) {
        int v = __shfl_up(incl, off);
        if (lane >= off) incl += v;
    }
    float fs = f;
    #pragma unroll
    for (int off = 1; off < 64; off <<= 1) fs += __shfl_xor(fs, off);
    if (lane == 63) wsum[w] = incl;
    if (lane == 0)  wsumf[w] = fs;
    __syncthreads();
    int woff = 0;
    #pragma unroll
    for (int j = 0; j < 4; ++j) if (j < w) woff += wsum[j];
    int excl = woff + incl - c;                    // tokens routed to e before token t*32
    if (t == 0) {
        int total = wsum[0] + wsum[1] + wsum[2] + wsum[3];
        float me = (wsumf[0] + wsumf[1] + wsumf[2] + wsumf[3]) / 8192.f;
        out[COUNTS_OFF + e] = (float)total;
        atomicAdd(out, me * ((float)total / 8192.f) * 64.f);   // l_aux (out[0] zeroed by k_main)
    }
    if (c == 0 || excl >= CAP) return;
    int run = excl;
    int base_s = t * 32;
    #pragma unroll 4
    for (int j = 0; j < 32; ++j) {
        if (run >= CAP) break;
        int s = base_s + j;
        if (eid[s] == e) {
            size_t idx = ((size_t)s * NE + e) * CAP + run;
            out[COMBINE_OFF + idx]  = gate_sel[s];
            out[DISPATCH_OFF + idx] = 1.0f;
            ++run;
        }
    }
}

extern "C" void kernel_launch(void* const* d_in, const int* in_sizes, int n_in,
                              void* d_out, int out_size, void* d_ws, size_t ws_size,
                              hipStream_t stream) {
    const float* in = (const float*)d_in[0];
    const float* wg = (const float*)d_in[1];
    float* out = (float*)d_out;

    float* gate_sel = (float*)d_ws;                  // 8192 f
    int*   eid      = (int*)(gate_sel + 8192);       // 8192 i
    int*   segcnt   = eid + 8192;                    // 64*512 i
    float* colpart  = (float*)(segcnt + NE * NSEG);  // 512*64 f

    k_main<<<640, 256, 0, stream>>>(in, wg, (f32x4*)out, gate_sel, eid, segcnt, colpart);
    k_scan_scatter<<<64, 256, 0, stream>>>(segcnt, gate_sel, eid, colpart, out);
}

// Round 9
// 614.791 us; speedup vs baseline: 1.0432x; 1.0432x over previous
//
#include <hip/hip_runtime.h>
#include <cstdint>
#include <cstddef>

#define S_TOK 8192
#define MDIM  2048
#define NE    64
#define CAP   128
#define NSEG  256   // 32-token segments
#define RT    64
#define KC    32

typedef float f32x4 __attribute__((ext_vector_type(4)));

// d_out float layout: [0]=l_aux | [1..+67108864)=combine | [..+67108864)=dispatch | [..+64)=exp_counts
static const size_t COMBINE_OFF  = 1;
static const size_t DISPATCH_OFF = 1 + 67108864ULL;
static const size_t COUNTS_OFF   = 1 + 2ULL * 67108864ULL;   // = 134217729

// ---------------------------------------------------------------- kernel 1: role-split
// 640 blocks. bid%5==4 (128 blocks): barrier-free nontemporal zero-fill of d_out
// (floats [0, 134217792); counts tail written by kernel 3). Other 512 blocks: R7's
// proven gemm (64r x 64e tile, split-K=4, thread 4r x 4e), barriers drain only 4
// staging loads. Gemm reads overlap fill writes; combined HBM floor ~96 us.
__global__ __launch_bounds__(256) void k_main(const float* __restrict__ in,
                                              const float* __restrict__ wg,
                                              f32x4* __restrict__ zout,
                                              float* __restrict__ part,
                                              float* __restrict__ colsum) {
    int t = threadIdx.x;
    int bid = blockIdx.x;
    const f32x4 z4 = {0.f, 0.f, 0.f, 0.f};
    if ((bid % 5) == 4) {                          // ---- fill role
        long i = (long)(bid / 5) * 256 + t;        // [0, 32768)
        #pragma unroll 4
        for (; i < 33554448L; i += 32768L)
            __builtin_nontemporal_store(z4, zout + i);
        return;
    }
    // ---- gemm role (identical to R7's k_gemm minus zero-stores)
    int g = (bid / 5) * 4 + (bid % 5);             // [0, 512)
    int bx = g & 127, by = g >> 7;                 // row-tile, k-quarter
    if (g == 0 && t < 64) colsum[t] = 0.f;
    __shared__ float in_lds[KC][RT + 4];
    __shared__ float wg_lds[KC][NE + 4];
    int r0 = bx * RT;
    int kbase = by * (MDIM / 4);
    int te = t & 15, tr = t >> 4;                  // e0 = te*4, rows = tr*4..tr*4+3
    int kq  = t & 7;                               // float4 group along k
    int row = t >> 3;                              // 0..31 (+32 second half)
    float acc[4][4] = {};
    for (int c = 0; c < 16; ++c) {
        int k0 = kbase + c * KC;
        float4 v0 = *(const float4*)(in + (size_t)(r0 + row) * MDIM + k0 + kq * 4);
        float4 v1 = *(const float4*)(in + (size_t)(r0 + row + 32) * MDIM + k0 + kq * 4);
        float4 w0 = *(const float4*)(wg + (size_t)row * MDIM + k0 + kq * 4);
        float4 w1 = *(const float4*)(wg + (size_t)(row + 32) * MDIM + k0 + kq * 4);
        in_lds[kq * 4 + 0][row] = v0.x; in_lds[kq * 4 + 1][row] = v0.y;
        in_lds[kq * 4 + 2][row] = v0.z; in_lds[kq * 4 + 3][row] = v0.w;
        in_lds[kq * 4 + 0][row + 32] = v1.x; in_lds[kq * 4 + 1][row + 32] = v1.y;
        in_lds[kq * 4 + 2][row + 32] = v1.z; in_lds[kq * 4 + 3][row + 32] = v1.w;
        wg_lds[kq * 4 + 0][row] = w0.x; wg_lds[kq * 4 + 1][row] = w0.y;
        wg_lds[kq * 4 + 2][row] = w0.z; wg_lds[kq * 4 + 3][row] = w0.w;
        wg_lds[kq * 4 + 0][row + 32] = w1.x; wg_lds[kq * 4 + 1][row + 32] = w1.y;
        wg_lds[kq * 4 + 2][row + 32] = w1.z; wg_lds[kq * 4 + 3][row + 32] = w1.w;
        __syncthreads();
        #pragma unroll
        for (int kk = 0; kk < KC; ++kk) {
            float4 a4 = *(const float4*)&in_lds[kk][tr * 4];
            float4 b4 = *(const float4*)&wg_lds[kk][te * 4];
            float a[4] = {a4.x, a4.y, a4.z, a4.w};
            float b[4] = {b4.x, b4.y, b4.z, b4.w};
            #pragma unroll
            for (int i = 0; i < 4; ++i)
                #pragma unroll
                for (int j = 0; j < 4; ++j)
                    acc[i][j] += a[i] * b[j];
        }
        __syncthreads();
    }
    #pragma unroll
    for (int i = 0; i < 4; ++i) {
        size_t base = ((size_t)by * S_TOK + r0 + tr * 4 + i) * NE + te * 4;
        *(float4*)(part + base) = make_float4(acc[i][0], acc[i][1], acc[i][2], acc[i][3]);
    }
}

// ---------------------------------------------------------------- softmax + argmax + seg histogram
__global__ __launch_bounds__(256) void k_softmax(const float* __restrict__ part,
                                                 float* __restrict__ colsum,
                                                 float* __restrict__ gate_sel,
                                                 int* __restrict__ eid,
                                                 int* __restrict__ segcnt) {
    __shared__ float ls[NE];
    __shared__ int hist[NE];
    int t = threadIdx.x;
    int lane = t & 63, w = t >> 6;
    if (t < NE) { ls[t] = 0.f; hist[t] = 0; }
    __syncthreads();
    float lsum = 0.f;
    for (int i = 0; i < 8; ++i) {
        int r = blockIdx.x * 32 + w * 8 + i;
        float v = part[(size_t)r * NE + lane]
                + part[(size_t)(S_TOK + r) * NE + lane]
                + part[(size_t)(2 * S_TOK + r) * NE + lane]
                + part[(size_t)(3 * S_TOK + r) * NE + lane];
        float m = v; int mi = lane;
        for (int off = 32; off > 0; off >>= 1) {
            float om = __shfl_xor(m, off);
            int   oi = __shfl_xor(mi, off);
            if (om > m || (om == m && oi < mi)) { m = om; mi = oi; }
        }
        float ex = expf(v - m);
        float s = ex;
        for (int off = 32; off > 0; off >>= 1) s += __shfl_xor(s, off);
        float gate = ex / s;
        lsum += gate;
        if (lane == mi) { gate_sel[r] = gate; eid[r] = mi; atomicAdd(&hist[mi], 1); }
    }
    atomicAdd(&ls[lane], lsum);
    __syncthreads();
    if (t < NE) {
        atomicAdd(&colsum[t], ls[t]);
        segcnt[t * NSEG + blockIdx.x] = hist[t];   // [e][seg]
    }
}

// ---------------------------------------------------------------- ranks + scatter + counts + l_aux
__global__ __launch_bounds__(256) void k_ranks_scatter(const int* __restrict__ eid,
                                                       const float* __restrict__ gate_sel,
                                                       const int* __restrict__ segcnt,
                                                       const float* __restrict__ colsum,
                                                       float* __restrict__ out) {
    __shared__ int wsum[4];
    int e = blockIdx.x;
    int t = threadIdx.x;
    int lane = t & 63, w = t >> 6;
    int c = segcnt[e * NSEG + t];
    int incl = c;
    #pragma unroll
    for (int off = 1; off < 64; off <<= 1) {
        int v = __shfl_up(incl, off);
        if (lane >= off) incl += v;
    }
    if (lane == 63) wsum[w] = incl;
    __syncthreads();
    int woff = 0;
    #pragma unroll
    for (int j = 0; j < 4; ++j) if (j < w) woff += wsum[j];
    int excl = woff + incl - c;                    // tokens for e before this segment
    if (t == 0) {
        int total = wsum[0] + wsum[1] + wsum[2] + wsum[3];
        out[COUNTS_OFF + e] = (float)total;
        float term = (colsum[e] / 8192.f) * ((float)total / 8192.f) * 64.f;
        atomicAdd(out, term);                      // l_aux (out[0] zeroed by k_main fills)
    }
    if (c == 0 || excl >= CAP) return;
    int run = excl;
    int base_s = t * 32;
    #pragma unroll 4
    for (int j = 0; j < 32; ++j) {
        if (run >= CAP) break;
        int s = base_s + j;
        if (eid[s] == e) {
            size_t idx = ((size_t)s * NE + e) * CAP + run;
            out[COMBINE_OFF + idx]  = gate_sel[s];
            out[DISPATCH_OFF + idx] = 1.0f;
            ++run;
        }
    }
}

extern "C" void kernel_launch(void* const* d_in, const int* in_sizes, int n_in,
                              void* d_out, int out_size, void* d_ws, size_t ws_size,
                              hipStream_t stream) {
    const float* in = (const float*)d_in[0];
    const float* wg = (const float*)d_in[1];
    float* out = (float*)d_out;

    float* colsum   = (float*)d_ws;                  // 64 f
    float* gate_sel = colsum + 64;                   // 8192 f
    int*   eid      = (int*)(gate_sel + 8192);       // 8192 i
    int*   segcnt   = eid + 8192;                    // 64*256 i
    float* part     = (float*)(segcnt + NE * NSEG);  // 4*8192*64 f

    k_main<<<640, 256, 0, stream>>>(in, wg, (f32x4*)out, part, colsum);
    k_softmax<<<256, 256, 0, stream>>>(part, colsum, gate_sel, eid, segcnt);
    k_ranks_scatter<<<64, 256, 0, stream>>>(eid, gate_sel, segcnt, colsum, out);
}